// Round 4
// baseline (43.494 us; speedup 1.0000x reference)
//
#include <hip/hip_runtime.h>

#define B_ROWS 16384
#define D_DIM  256
#define C_CLS  4096
#define NBLK   1024   // k_class blocks: 4 waves each -> 4096 waves, one per class
#define CLAMP_LO 1e-12f
#define CLAMP_HI 1e12f

__device__ __forceinline__ float wave_reduce_sum(float v) {
    for (int o = 32; o > 0; o >>= 1) v += __shfl_xor(v, o, 64);
    return v;
}
__device__ __forceinline__ int wave_reduce_min(int v) {
    for (int o = 32; o > 0; o >>= 1) v = min(v, __shfl_xor(v, o, 64));
    return v;
}

// K1: one-block counting sort of 16K labels into per-class buckets.
// Also computes counts, offsets, first occupied class, zeroes doneCount.
__global__ void __launch_bounds__(1024) k_sort(const int* __restrict__ labels,
                                               int* __restrict__ bucket,
                                               int* __restrict__ offsets,
                                               int* __restrict__ counts,
                                               int* __restrict__ firstCls,
                                               int* __restrict__ doneCount) {
    __shared__ int hist[C_CLS];   // histogram, then reused as scatter cursor
    __shared__ int wsum[16];
    __shared__ int firstRed;
    const int t = threadIdx.x;
    const int lane = t & 63;
    const int wv = t >> 6;

    #pragma unroll
    for (int i = 0; i < 4; ++i) hist[t + 1024 * i] = 0;
    if (t == 0) firstRed = 0x7FFFFFFF;
    __syncthreads();

    int lab[16];
    #pragma unroll
    for (int i = 0; i < 16; ++i) {
        lab[i] = labels[t + 1024 * i];
        atomicAdd(&hist[lab[i]], 1);
    }
    __syncthreads();

    // thread t owns hist[4t..4t+3]
    const int c0 = hist[4 * t], c1 = hist[4 * t + 1],
              c2 = hist[4 * t + 2], c3 = hist[4 * t + 3];
    const int s = c0 + c1 + c2 + c3;

    // first occupied class (min index with count > 0)
    int fm = 0x7FFFFFFF;
    if (c3 > 0) fm = 4 * t + 3;
    if (c2 > 0) fm = 4 * t + 2;
    if (c1 > 0) fm = 4 * t + 1;
    if (c0 > 0) fm = 4 * t;
    fm = wave_reduce_min(fm);
    if (lane == 0) atomicMin(&firstRed, fm);

    // block-wide inclusive scan of per-thread sums
    int incl = s;
    #pragma unroll
    for (int o = 1; o < 64; o <<= 1) {
        int u = __shfl_up(incl, o, 64);
        if (lane >= o) incl += u;
    }
    if (lane == 63) wsum[wv] = incl;
    __syncthreads();
    if (wv == 0) {
        int w = (lane < 16) ? wsum[lane] : 0;
        #pragma unroll
        for (int o = 1; o < 16; o <<= 1) {
            int u = __shfl_up(w, o, 64);
            if (lane >= o) w += u;
        }
        if (lane < 16) wsum[lane] = w;
    }
    __syncthreads();
    const int base = (wv > 0) ? wsum[wv - 1] : 0;
    const int excl = base + incl - s;

    const int o0 = excl, o1 = o0 + c0, o2 = o1 + c1, o3 = o2 + c2;
    *reinterpret_cast<int4*>(&counts[4 * t])  = make_int4(c0, c1, c2, c3);
    *reinterpret_cast<int4*>(&offsets[4 * t]) = make_int4(o0, o1, o2, o3);
    if (t == 0) { *firstCls = firstRed; *doneCount = 0; }

    // reuse hist as scatter cursor
    hist[4 * t] = o0; hist[4 * t + 1] = o1;
    hist[4 * t + 2] = o2; hist[4 * t + 3] = o3;
    __syncthreads();

    #pragma unroll
    for (int i = 0; i < 16; ++i) {
        const int pos = atomicAdd(&hist[lab[i]], 1);
        bucket[pos] = t + 1024 * i;
    }
}

// K2: one WAVE per class (lane = 4 dims as float4). Single pass over member
// rows via sorted bucket with software-pipelined index prefetch. Last block
// reduces all per-class contributions to the final scalar.
__global__ void __launch_bounds__(256) k_class(const float* __restrict__ x,
                                               const float* __restrict__ centers,
                                               const int* __restrict__ bucket,
                                               const int* __restrict__ offsets,
                                               const int* __restrict__ counts,
                                               const int* __restrict__ firstCls,
                                               float* __restrict__ contrib,
                                               int* __restrict__ doneCount,
                                               float* __restrict__ out) {
    const int wv = threadIdx.x >> 6;
    const int lane = threadIdx.x & 63;
    const int c = blockIdx.x * 4 + wv;
    const int cnt = counts[c];

    if (cnt > 0) {
        const int off = offsets[c];
        const float4* __restrict__ X = reinterpret_cast<const float4*>(x);
        float sx = 0.0f, sy = 0.0f, sz = 0.0f, sw = 0.0f, q = 0.0f;
        int b = bucket[off];
        for (int i = 0; i < cnt; ++i) {
            const int bn = (i + 1 < cnt) ? bucket[off + i + 1] : 0;
            const float4 v = X[(size_t)b * (D_DIM / 4) + lane];
            sx += v.x; sy += v.y; sz += v.z; sw += v.w;
            q += v.x * v.x + v.y * v.y + v.z * v.z + v.w * v.w;
            b = bn;
        }
        const float inv = 1.0f / (float)cnt;
        float n0 = sx * inv, n1 = sy * inv, n2 = sz * inv, n3 = sw * inv;
        if (c != *firstCls) {
            const float4 cv =
                reinterpret_cast<const float4*>(centers)[(size_t)c * (D_DIM / 4) + lane];
            n0 = 0.5f * cv.x + 0.5f * n0;
            n1 = 0.5f * cv.y + 0.5f * n1;
            n2 = 0.5f * cv.z + 0.5f * n2;
            n3 = 0.5f * cv.w + 0.5f * n3;
        }
        const float A0 = wave_reduce_sum(q);
        const float A1 = wave_reduce_sum(sx * n0 + sy * n1 + sz * n2 + sw * n3);
        const float A2 = wave_reduce_sum(n0 * n0 + n1 * n1 + n2 * n2 + n3 * n3);
        if (lane == 0) {
            float S = A0 - 2.0f * A1 + (float)cnt * A2;
            // per-row clamp only binds where the closed form gives exactly 0
            // (singleton first class) -> class-level clamp is exact
            S = fminf(fmaxf(S, CLAMP_LO), CLAMP_HI);
            contrib[c] = (S + (float)(B_ROWS - cnt) * CLAMP_LO) / (float)cnt;
        }
    } else {
        if (lane == 0) contrib[c] = (float)B_ROWS * CLAMP_LO;  // denom = 1
    }

    // ---- last-block final reduction ----
    __shared__ int isLast;
    __syncthreads();
    if (threadIdx.x == 0) {
        __threadfence();                      // release contrib writes
        const int old = atomicAdd(doneCount, 1);
        isLast = (old == (int)gridDim.x - 1);
    }
    __syncthreads();
    if (isLast) {
        __threadfence();                      // acquire others' contrib writes
        float acc = 0.0f;
        const float4* cf = reinterpret_cast<const float4*>(contrib);
        for (int i = threadIdx.x; i < C_CLS / 4; i += 256) {
            const float4 v = cf[i];
            acc += v.x + v.y + v.z + v.w;
        }
        acc = wave_reduce_sum(acc);
        __shared__ float red[4];
        if ((threadIdx.x & 63) == 0) red[threadIdx.x >> 6] = acc;
        __syncthreads();
        if (threadIdx.x == 0) {
            const float total = red[0] + red[1] + red[2] + red[3];
            out[0] = total / (float)((size_t)C_CLS * D_DIM);
        }
    }
}

extern "C" void kernel_launch(void* const* d_in, const int* in_sizes, int n_in,
                              void* d_out, int out_size, void* d_ws, size_t ws_size,
                              hipStream_t stream) {
    const float* x       = (const float*)d_in[0];
    const float* centers = (const float*)d_in[1];
    const int*   labels  = (const int*)d_in[2];
    float* out = (float*)d_out;

    char* ws = (char*)d_ws;
    int*   bucket    = (int*)ws;                                        // 16384
    int*   offsets   = (int*)(ws + B_ROWS * sizeof(int));               // 4096
    int*   counts    = (int*)(ws + (B_ROWS + C_CLS) * sizeof(int));     // 4096
    float* contrib   = (float*)(ws + (B_ROWS + 2 * C_CLS) * sizeof(int)); // 4096
    int*   firstCls  = (int*)(ws + (B_ROWS + 3 * C_CLS) * sizeof(int));
    int*   doneCount = firstCls + 1;

    k_sort <<<1, 1024, 0, stream>>>(labels, bucket, offsets, counts, firstCls,
                                    doneCount);
    k_class<<<NBLK, 256, 0, stream>>>(x, centers, bucket, offsets, counts,
                                      firstCls, contrib, doneCount, out);
}

// Round 5
// 26.689 us; speedup vs baseline: 1.6297x; 1.6297x over previous
//
#include <hip/hip_runtime.h>

#define B_ROWS 16384
#define D_DIM  256
#define C_CLS  4096
#define CLAMP_LO 1e-12f
#define CLAMP_HI 1e12f

__device__ __forceinline__ float wave_reduce_sum(float v) {
    for (int o = 32; o > 0; o >>= 1) v += __shfl_xor(v, o, 64);
    return v;
}
__device__ __forceinline__ int wave_reduce_min(int v) {
    for (int o = 32; o > 0; o >>= 1) v = min(v, __shfl_xor(v, o, 64));
    return v;
}

// K1: one-block counting sort of 16K labels into per-class buckets.
// Also computes counts, offsets, first occupied class. No global memsets needed.
__global__ void __launch_bounds__(1024) k_sort(const int* __restrict__ labels,
                                               int* __restrict__ bucket,
                                               int* __restrict__ offsets,
                                               int* __restrict__ counts,
                                               int* __restrict__ firstCls) {
    __shared__ int hist[C_CLS];   // histogram, then reused as scatter cursor
    __shared__ int wsum[16];
    __shared__ int firstRed;
    const int t = threadIdx.x;
    const int lane = t & 63;
    const int wv = t >> 6;

    #pragma unroll
    for (int i = 0; i < 4; ++i) hist[t + 1024 * i] = 0;
    if (t == 0) firstRed = 0x7FFFFFFF;
    __syncthreads();

    int lab[16];
    #pragma unroll
    for (int i = 0; i < 16; ++i) {
        lab[i] = labels[t + 1024 * i];
        atomicAdd(&hist[lab[i]], 1);
    }
    __syncthreads();

    const int c0 = hist[4 * t], c1 = hist[4 * t + 1],
              c2 = hist[4 * t + 2], c3 = hist[4 * t + 3];
    const int s = c0 + c1 + c2 + c3;

    int fm = 0x7FFFFFFF;
    if (c3 > 0) fm = 4 * t + 3;
    if (c2 > 0) fm = 4 * t + 2;
    if (c1 > 0) fm = 4 * t + 1;
    if (c0 > 0) fm = 4 * t;
    fm = wave_reduce_min(fm);
    if (lane == 0) atomicMin(&firstRed, fm);

    int incl = s;
    #pragma unroll
    for (int o = 1; o < 64; o <<= 1) {
        int u = __shfl_up(incl, o, 64);
        if (lane >= o) incl += u;
    }
    if (lane == 63) wsum[wv] = incl;
    __syncthreads();
    if (wv == 0) {
        int w = (lane < 16) ? wsum[lane] : 0;
        #pragma unroll
        for (int o = 1; o < 16; o <<= 1) {
            int u = __shfl_up(w, o, 64);
            if (lane >= o) w += u;
        }
        if (lane < 16) wsum[lane] = w;
    }
    __syncthreads();
    const int base = (wv > 0) ? wsum[wv - 1] : 0;
    const int excl = base + incl - s;

    const int o0 = excl, o1 = o0 + c0, o2 = o1 + c1, o3 = o2 + c2;
    *reinterpret_cast<int4*>(&counts[4 * t])  = make_int4(c0, c1, c2, c3);
    *reinterpret_cast<int4*>(&offsets[4 * t]) = make_int4(o0, o1, o2, o3);
    if (t == 0) *firstCls = firstRed;

    hist[4 * t] = o0; hist[4 * t + 1] = o1;
    hist[4 * t + 2] = o2; hist[4 * t + 3] = o3;
    __syncthreads();

    #pragma unroll
    for (int i = 0; i < 16; ++i) {
        const int pos = atomicAdd(&hist[lab[i]], 1);
        bucket[pos] = t + 1024 * i;
    }
}

// K2: one BLOCK per class; member rows split across the 4 waves (wave wv takes
// rows wv, wv+4, ...), lane holds 4 dims as float4. Partials combined via LDS.
// Dependent chain per wave ~= ceil(cnt/4) row loads (~1 for mean cnt=4).
__global__ void __launch_bounds__(256) k_class(const float* __restrict__ x,
                                               const float* __restrict__ centers,
                                               const int* __restrict__ bucket,
                                               const int* __restrict__ offsets,
                                               const int* __restrict__ counts,
                                               const int* __restrict__ firstCls,
                                               float* __restrict__ contrib) {
    const int c = blockIdx.x;
    const int t = threadIdx.x;
    const int wv = t >> 6;
    const int lane = t & 63;
    const int cnt = counts[c];
    if (cnt == 0) {
        if (t == 0) contrib[c] = (float)B_ROWS * CLAMP_LO;  // denom = 1
        return;
    }
    const int off = offsets[c];
    const float4* __restrict__ X = reinterpret_cast<const float4*>(x);

    float sx = 0.0f, sy = 0.0f, sz = 0.0f, sw = 0.0f, q = 0.0f;
    for (int i = wv; i < cnt; i += 4) {
        const int b = bucket[off + i];
        const float4 v = X[(size_t)b * (D_DIM / 4) + lane];
        sx += v.x; sy += v.y; sz += v.z; sw += v.w;
        q += v.x * v.x + v.y * v.y + v.z * v.z + v.w * v.w;
    }

    __shared__ float4 sh_s[4][64];
    __shared__ float sh_q[4];
    sh_s[wv][lane] = make_float4(sx, sy, sz, sw);
    const float qq = wave_reduce_sum(q);
    if (lane == 0) sh_q[wv] = qq;
    __syncthreads();

    if (wv == 0) {
        const float4 p0 = sh_s[0][lane], p1 = sh_s[1][lane],
                     p2 = sh_s[2][lane], p3 = sh_s[3][lane];
        const float t0 = p0.x + p1.x + p2.x + p3.x;
        const float t1 = p0.y + p1.y + p2.y + p3.y;
        const float t2 = p0.z + p1.z + p2.z + p3.z;
        const float t3 = p0.w + p1.w + p2.w + p3.w;
        const float Q = sh_q[0] + sh_q[1] + sh_q[2] + sh_q[3];

        const float inv = 1.0f / (float)cnt;
        float n0 = t0 * inv, n1 = t1 * inv, n2 = t2 * inv, n3 = t3 * inv;
        if (c != *firstCls) {
            const float4 cv =
                reinterpret_cast<const float4*>(centers)[(size_t)c * (D_DIM / 4) + lane];
            n0 = 0.5f * cv.x + 0.5f * n0;
            n1 = 0.5f * cv.y + 0.5f * n1;
            n2 = 0.5f * cv.z + 0.5f * n2;
            n3 = 0.5f * cv.w + 0.5f * n3;
        }
        const float A1 = wave_reduce_sum(t0 * n0 + t1 * n1 + t2 * n2 + t3 * n3);
        const float A2 = wave_reduce_sum(n0 * n0 + n1 * n1 + n2 * n2 + n3 * n3);
        if (lane == 0) {
            float S = Q - 2.0f * A1 + (float)cnt * A2;
            // per-row clamp only binds where the closed form gives exactly 0
            // (singleton first class) -> class-level clamp is exact
            S = fminf(fmaxf(S, CLAMP_LO), CLAMP_HI);
            contrib[c] = (S + (float)(B_ROWS - cnt) * CLAMP_LO) / (float)cnt;
        }
    }
}

// K3: sum contributions, scale. (Separate dispatch = free device-wide release;
// fused last-block version cost ~1024 device-scope fences -> 15 us regression.)
__global__ void __launch_bounds__(256) k_final(const float* __restrict__ contrib,
                                               float* __restrict__ out) {
    const int t = threadIdx.x;
    float acc = 0.0f;
    for (int i = t; i < C_CLS / 4; i += 256) {
        const float4 v = reinterpret_cast<const float4*>(contrib)[i];
        acc += v.x + v.y + v.z + v.w;
    }
    acc = wave_reduce_sum(acc);
    __shared__ float red[4];
    if ((t & 63) == 0) red[t >> 6] = acc;
    __syncthreads();
    if (t == 0) {
        const float total = red[0] + red[1] + red[2] + red[3];
        out[0] = total / (float)((size_t)C_CLS * D_DIM);
    }
}

extern "C" void kernel_launch(void* const* d_in, const int* in_sizes, int n_in,
                              void* d_out, int out_size, void* d_ws, size_t ws_size,
                              hipStream_t stream) {
    const float* x       = (const float*)d_in[0];
    const float* centers = (const float*)d_in[1];
    const int*   labels  = (const int*)d_in[2];
    float* out = (float*)d_out;

    char* ws = (char*)d_ws;
    int*   bucket   = (int*)ws;                                         // 16384
    int*   offsets  = (int*)(ws + B_ROWS * sizeof(int));                // 4096
    int*   counts   = (int*)(ws + (B_ROWS + C_CLS) * sizeof(int));      // 4096
    float* contrib  = (float*)(ws + (B_ROWS + 2 * C_CLS) * sizeof(int)); // 4096
    int*   firstCls = (int*)(ws + (B_ROWS + 3 * C_CLS) * sizeof(int));

    k_sort <<<1, 1024, 0, stream>>>(labels, bucket, offsets, counts, firstCls);
    k_class<<<C_CLS, 256, 0, stream>>>(x, centers, bucket, offsets, counts,
                                       firstCls, contrib);
    k_final<<<1, 256, 0, stream>>>(contrib, out);
}

// Round 6
// 24.606 us; speedup vs baseline: 1.7676x; 1.0847x over previous
//
#include <hip/hip_runtime.h>

#define B_ROWS 16384
#define D_DIM  256
#define C_CLS  4096
#define CLAMP_LO 1e-12f
#define CLAMP_HI 1e12f

__device__ __forceinline__ float wave_reduce_sum(float v) {
    for (int o = 32; o > 0; o >>= 1) v += __shfl_xor(v, o, 64);
    return v;
}
__device__ __forceinline__ int wave_reduce_min(int v) {
    for (int o = 32; o > 0; o >>= 1) v = min(v, __shfl_xor(v, o, 64));
    return v;
}

// K1: one-block counting sort of 16K labels into per-class buckets.
// Emits packed per-class metadata: pairs[c] = {offset, cnt | (isFirst<<31)}.
__global__ void __launch_bounds__(1024) k_sort(const int* __restrict__ labels,
                                               int* __restrict__ bucket,
                                               int2* __restrict__ pairs) {
    __shared__ int hist[C_CLS];   // histogram, then reused as scatter cursor
    __shared__ int wsum[16];
    __shared__ int firstRed;
    const int t = threadIdx.x;
    const int lane = t & 63;
    const int wv = t >> 6;

    #pragma unroll
    for (int i = 0; i < 4; ++i) hist[t + 1024 * i] = 0;
    if (t == 0) firstRed = 0x7FFFFFFF;
    __syncthreads();

    // 16 labels/thread via 4x int4 loads
    const int4* __restrict__ L4 = reinterpret_cast<const int4*>(labels);
    int4 lv[4];
    #pragma unroll
    for (int j = 0; j < 4; ++j) {
        lv[j] = L4[t + 1024 * j];
        atomicAdd(&hist[lv[j].x], 1);
        atomicAdd(&hist[lv[j].y], 1);
        atomicAdd(&hist[lv[j].z], 1);
        atomicAdd(&hist[lv[j].w], 1);
    }
    __syncthreads();

    // thread t owns classes 4t..4t+3
    const int c0 = hist[4 * t], c1 = hist[4 * t + 1],
              c2 = hist[4 * t + 2], c3 = hist[4 * t + 3];
    const int s = c0 + c1 + c2 + c3;

    int fm = 0x7FFFFFFF;
    if (c3 > 0) fm = 4 * t + 3;
    if (c2 > 0) fm = 4 * t + 2;
    if (c1 > 0) fm = 4 * t + 1;
    if (c0 > 0) fm = 4 * t;
    fm = wave_reduce_min(fm);
    if (lane == 0) atomicMin(&firstRed, fm);

    // block-wide inclusive scan of per-thread sums
    int incl = s;
    #pragma unroll
    for (int o = 1; o < 64; o <<= 1) {
        int u = __shfl_up(incl, o, 64);
        if (lane >= o) incl += u;
    }
    if (lane == 63) wsum[wv] = incl;
    __syncthreads();
    if (wv == 0) {
        int w = (lane < 16) ? wsum[lane] : 0;
        #pragma unroll
        for (int o = 1; o < 16; o <<= 1) {
            int u = __shfl_up(w, o, 64);
            if (lane >= o) w += u;
        }
        if (lane < 16) wsum[lane] = w;
    }
    __syncthreads();
    const int base = (wv > 0) ? wsum[wv - 1] : 0;
    const int excl = base + incl - s;

    const int o0 = excl, o1 = o0 + c0, o2 = o1 + c1, o3 = o2 + c2;
    const int fr = firstRed;   // finalized: atomicMin above, 2 syncs since
    const int y0 = c0 | ((4 * t + 0 == fr) ? 0x80000000 : 0);
    const int y1 = c1 | ((4 * t + 1 == fr) ? 0x80000000 : 0);
    const int y2 = c2 | ((4 * t + 2 == fr) ? 0x80000000 : 0);
    const int y3 = c3 | ((4 * t + 3 == fr) ? 0x80000000 : 0);
    int4* P4 = reinterpret_cast<int4*>(pairs);
    P4[2 * t]     = make_int4(o0, y0, o1, y1);
    P4[2 * t + 1] = make_int4(o2, y2, o3, y3);

    // reuse hist as scatter cursor
    hist[4 * t] = o0; hist[4 * t + 1] = o1;
    hist[4 * t + 2] = o2; hist[4 * t + 3] = o3;
    __syncthreads();

    #pragma unroll
    for (int j = 0; j < 4; ++j) {
        const int r = 4 * (t + 1024 * j);
        int pos;
        pos = atomicAdd(&hist[lv[j].x], 1); bucket[pos] = r + 0;
        pos = atomicAdd(&hist[lv[j].y], 1); bucket[pos] = r + 1;
        pos = atomicAdd(&hist[lv[j].z], 1); bucket[pos] = r + 2;
        pos = atomicAdd(&hist[lv[j].w], 1); bucket[pos] = r + 3;
    }
}

// K2: one 128-thread block (2 waves) per class; 4096 blocks = exactly full
// residency (32 waves/CU) in one round. Lane holds 4 dims as float4; member
// rows split across the 2 waves; partials combined via LDS.
__global__ void __launch_bounds__(128) k_class(const float* __restrict__ x,
                                               const float* __restrict__ centers,
                                               const int* __restrict__ bucket,
                                               const int2* __restrict__ pairs,
                                               float* __restrict__ contrib) {
    const int c = blockIdx.x;
    const int t = threadIdx.x;
    const int wv = t >> 6;
    const int lane = t & 63;

    const int2 p = pairs[c];
    const int off = p.x;
    const int cnt = p.y & 0x7FFFFFFF;
    const bool isFirst = (p.y < 0);
    if (cnt == 0) {
        if (t == 0) contrib[c] = (float)B_ROWS * CLAMP_LO;  // denom = 1
        return;
    }
    const float4* __restrict__ X = reinterpret_cast<const float4*>(x);

    float sx = 0.0f, sy = 0.0f, sz = 0.0f, sw = 0.0f, q = 0.0f;
    for (int i = wv; i < cnt; i += 2) {
        const int b = bucket[off + i];
        const float4 v = X[(size_t)b * (D_DIM / 4) + lane];
        sx += v.x; sy += v.y; sz += v.z; sw += v.w;
        q += v.x * v.x + v.y * v.y + v.z * v.z + v.w * v.w;
    }

    __shared__ float4 sh_s[2][64];
    __shared__ float sh_q[2];
    sh_s[wv][lane] = make_float4(sx, sy, sz, sw);
    const float qq = wave_reduce_sum(q);
    if (lane == 0) sh_q[wv] = qq;
    __syncthreads();

    if (wv == 0) {
        const float4 p0 = sh_s[0][lane], p1 = sh_s[1][lane];
        const float t0 = p0.x + p1.x;
        const float t1 = p0.y + p1.y;
        const float t2 = p0.z + p1.z;
        const float t3 = p0.w + p1.w;
        const float Q = sh_q[0] + sh_q[1];

        const float inv = 1.0f / (float)cnt;
        float n0 = t0 * inv, n1 = t1 * inv, n2 = t2 * inv, n3 = t3 * inv;
        if (!isFirst) {
            const float4 cv =
                reinterpret_cast<const float4*>(centers)[(size_t)c * (D_DIM / 4) + lane];
            n0 = 0.5f * cv.x + 0.5f * n0;
            n1 = 0.5f * cv.y + 0.5f * n1;
            n2 = 0.5f * cv.z + 0.5f * n2;
            n3 = 0.5f * cv.w + 0.5f * n3;
        }
        const float A1 = wave_reduce_sum(t0 * n0 + t1 * n1 + t2 * n2 + t3 * n3);
        const float A2 = wave_reduce_sum(n0 * n0 + n1 * n1 + n2 * n2 + n3 * n3);
        if (lane == 0) {
            float S = Q - 2.0f * A1 + (float)cnt * A2;
            // per-row clamp only binds where the closed form gives exactly 0
            // (singleton first class) -> class-level clamp is exact
            S = fminf(fmaxf(S, CLAMP_LO), CLAMP_HI);
            contrib[c] = (S + (float)(B_ROWS - cnt) * CLAMP_LO) / (float)cnt;
        }
    }
}

// K3: sum contributions, scale. (Separate dispatch = free device-wide barrier;
// fused variants pay same-address atomic serialization / fence storms.)
__global__ void __launch_bounds__(256) k_final(const float* __restrict__ contrib,
                                               float* __restrict__ out) {
    const int t = threadIdx.x;
    float acc = 0.0f;
    for (int i = t; i < C_CLS / 4; i += 256) {
        const float4 v = reinterpret_cast<const float4*>(contrib)[i];
        acc += v.x + v.y + v.z + v.w;
    }
    acc = wave_reduce_sum(acc);
    __shared__ float red[4];
    if ((t & 63) == 0) red[t >> 6] = acc;
    __syncthreads();
    if (t == 0) {
        const float total = red[0] + red[1] + red[2] + red[3];
        out[0] = total / (float)((size_t)C_CLS * D_DIM);
    }
}

extern "C" void kernel_launch(void* const* d_in, const int* in_sizes, int n_in,
                              void* d_out, int out_size, void* d_ws, size_t ws_size,
                              hipStream_t stream) {
    const float* x       = (const float*)d_in[0];
    const float* centers = (const float*)d_in[1];
    const int*   labels  = (const int*)d_in[2];
    float* out = (float*)d_out;

    char* ws = (char*)d_ws;
    int*   bucket  = (int*)ws;                                  // 64 KB
    int2*  pairs   = (int2*)(ws + B_ROWS * sizeof(int));        // 32 KB
    float* contrib = (float*)(ws + B_ROWS * sizeof(int) + C_CLS * sizeof(int2)); // 16 KB

    k_sort <<<1, 1024, 0, stream>>>(labels, bucket, pairs);
    k_class<<<C_CLS, 128, 0, stream>>>(x, centers, bucket, pairs, contrib);
    k_final<<<1, 256, 0, stream>>>(contrib, out);
}